// Round 5
// baseline (149.458 us; speedup 1.0000x reference)
//
#include <hip/hip_runtime.h>
#include <hip/hip_bf16.h>

typedef __attribute__((ext_vector_type(8))) short short8;
typedef __attribute__((ext_vector_type(4))) float f32x4;

#define NT 65536

__device__ __forceinline__ unsigned short f2bf(float f) {
    union { float f; unsigned int u; } v; v.f = f;
    unsigned int u = v.u;
    unsigned int r = (u + 0x7fffu + ((u >> 16) & 1u)) >> 16;  // RNE
    return (unsigned short)r;
}

__device__ __forceinline__ unsigned int cvt_pk_bf16(float lo, float hi) {
    unsigned int r;
    asm("v_cvt_pk_bf16_f32 %0, %1, %2" : "=v"(r) : "v"(lo), "v"(hi));
    return r;
}

// ---------------- prep: bf16 B panel + per-k params ----------------
// Panel row n: k16 = n>>5, typ = (n>>4)&1, r = n&15 -> k = k16*16 + r; typ0 = w, typ1 = beta.
// prm per source (5*256 floats): [0:256)=||w_k||^2, [256)=gam^2, [512)=eta^2, [768)=alpha, [1024)=sig^2
__global__ void prep_kernel(const float* __restrict__ w, const float* __restrict__ beta,
                            const float* __restrict__ alpha, const float* __restrict__ sig,
                            const float* __restrict__ eta, const float* __restrict__ gam,
                            unsigned short* __restrict__ bc, float* __restrict__ prm, int P) {
    __shared__ float red[2];
    const int n = blockIdx.x;          // 0..511
    const int tid = threadIdx.x;       // 128 threads
    const int k16 = n >> 5;
    const int typ = (n >> 4) & 1;
    const int k = k16 * 16 + (n & 15);
    const bool isw = (typ == 0);
    const float* src = (isw ? w : beta) + (size_t)k * P;
    unsigned short* dst = bc + (size_t)n * P;
    float ss = 0.f;
    for (int c = tid; c < P; c += 128) {
        float f = src[c];
        dst[c] = f2bf(f);
        if (isw) ss += f * f;
    }
#pragma unroll
    for (int m = 1; m < 64; m <<= 1) ss += __shfl_xor(ss, m);
    if ((tid & 63) == 0) red[tid >> 6] = ss;
    __syncthreads();
    if (isw && tid == 0) prm[k] = red[0] + red[1];
    if (n == 0) {
        for (int kk = tid; kk < 256; kk += 128) {
            float g = gam[kk], e = eta[kk];
            prm[256 + kk]  = g * g;
            prm[512 + kk]  = e * e;
            prm[768 + kk]  = alpha[kk];
            prm[1024 + kk] = sig[kk] * sig[kk];
        }
    }
}

// ---------------- fused per-source: B-in-registers GEMM + RBF epilogue ----------------
// 512 thr (8 waves). grid 256: h = bx/NRG (k-group), rg = bx%NRG. Siblings (same rg,
// different h) differ by NRG≡0 mod 8 -> SAME XCD -> L2/L3 dedup of x re-reads.
// P=512: wave=(kset=wv>>1, pp=wv&1): owns w+beta strips of 16 k's x k-dim HALF.
//        Bf[2][8]=64 VGPRs resident. Partner waves exchange partial acc via dead-LDS.
// P=256/128: wave owns w+beta strips of 16 k's, full k-dim (Bf = 64/32 VGPRs), KSPLIT=2.
// A tile (64 rows x P) staged fp32->bf16 into double-buffered LDS; granule loads issued
// WIN steps ahead of cvt+ds_write. LDS 16B slots XOR-swizzled: phys = slot ^ (row&7).
// MFMA swapped: mfma(Bf, af) -> lane holds col = x-row (l15), row = k (4*l4 + j).
template<int P>
__global__ __launch_bounds__(512, 2)
void fused_src(const float* __restrict__ x, const unsigned short* __restrict__ Bc,
               const float* __restrict__ prm, float* __restrict__ pws) {
    constexpr int  KSPLIT = (P == 512) ? 4 : 2;
    constexpr bool PPS    = (P == 512);
    constexpr int  KSW    = PPS ? P / 64 : P / 32;   // k-dim steps per wave: 8,8,4
    constexpr int  IST    = P / 64;                  // staging granules/thread: 8,4,2
    constexpr int  WIN    = (IST < 4) ? IST : 4;     // load->consume distance
    constexpr int  NRG    = 256 / KSPLIT;            // 64,128,128
    constexpr int  T      = 1024 / NRG;              // 16,8,8

    __shared__ unsigned short As[2][64 * P];
    __shared__ float xn2s[2][64];
    __shared__ float part[8][64][3];

    const int bx = blockIdx.x;
    const int h  = bx / NRG;
    const int rg = bx % NRG;
    const int tid = threadIdx.x, lane = tid & 63, wv = tid >> 6;
    const int l15 = lane & 15, l4 = lane >> 4;

    int k16, pp, kset;
    if (PPS) { kset = wv >> 1; pp = wv & 1; k16 = h * 4 + kset; }
    else     { kset = wv;      pp = 0;      k16 = h * 8 + wv; }
    const int ppoff = PPS ? pp * (P / 2) : 0;

    // ---- resident B fragments ----
    short8 Bf[2][KSW];
#pragma unroll
    for (int typ = 0; typ < 2; typ++)
#pragma unroll
        for (int ks = 0; ks < KSW; ks++)
            Bf[typ][ks] = *(const short8*)(Bc + (size_t)(k16 * 32 + typ * 16 + l15) * P
                                           + ppoff + ks * 32 + l4 * 8);

    // ---- per-lane params for k = k16*16 + 4*l4 + j ----
    const int kb = k16 * 16 + 4 * l4;
    const f32x4 wn2 = *(const f32x4*)(prm + kb);
    const f32x4 g2  = *(const f32x4*)(prm + 256 + kb);
    const f32x4 hv  = *(const f32x4*)(prm + 512 + kb);
    const f32x4 alv = *(const f32x4*)(prm + 768 + kb);
    const f32x4 s2v = *(const f32x4*)(prm + 1024 + kb);

    // staging geometry: thread -> row = tid>>3 (0..63), 16B slots (tid&7)+8i
    const int srow = tid >> 3;
    const int ssl0 = tid & 7;

    // ---- prologue: stage tile 0 into buf 0 ----
    {
        const int row0 = rg * 64;
        float ssacc = 0.f;
#pragma unroll
        for (int i = 0; i < IST; i++) {
            const float* gp = x + (size_t)(row0 + srow) * P + (ssl0 + 8 * i) * 8;
            float4 a0 = *(const float4*)(gp);
            float4 a1 = *(const float4*)(gp + 4);
            ssacc += a0.x*a0.x + a0.y*a0.y + a0.z*a0.z + a0.w*a0.w
                   + a1.x*a1.x + a1.y*a1.y + a1.z*a1.z + a1.w*a1.w;
            uint4 pk = { cvt_pk_bf16(a0.x, a0.y), cvt_pk_bf16(a0.z, a0.w),
                         cvt_pk_bf16(a1.x, a1.y), cvt_pk_bf16(a1.z, a1.w) };
            const int slot = ssl0 + 8 * i;
            *(uint4*)(&As[0][srow * P + ((slot ^ (srow & 7)) << 3)]) = pk;
        }
        ssacc += __shfl_xor(ssacc, 1);
        ssacc += __shfl_xor(ssacc, 2);
        ssacc += __shfl_xor(ssacc, 4);
        if (ssl0 == 0) xn2s[0][srow] = ssacc;
    }
    __syncthreads();

    int buf = 0;
    for (int tt = 0; tt < T; tt++) {
        const int row0 = (rg + NRG * tt) * 64;
        const bool more = (tt < T - 1);
        const int nrow0 = (rg + NRG * (tt + 1)) * 64;

        f32x4 acc[2][4];
#pragma unroll
        for (int typ = 0; typ < 2; typ++)
#pragma unroll
            for (int rf = 0; rf < 4; rf++) acc[typ][rf] = (f32x4){0.f, 0.f, 0.f, 0.f};

        float4 ga[WIN], gb[WIN];
        float ssn = 0.f;

#pragma unroll
        for (int ks = 0; ks < KSW; ks++) {
            // consume granule ks-WIN: cvt + swizzled ds_write into buf^1
            if (more && ks >= WIN && (ks - WIN) < IST) {
                const int i = ks - WIN;
                float4 a0 = ga[i % WIN], a1 = gb[i % WIN];
                ssn += a0.x*a0.x + a0.y*a0.y + a0.z*a0.z + a0.w*a0.w
                     + a1.x*a1.x + a1.y*a1.y + a1.z*a1.z + a1.w*a1.w;
                uint4 pk = { cvt_pk_bf16(a0.x, a0.y), cvt_pk_bf16(a0.z, a0.w),
                             cvt_pk_bf16(a1.x, a1.y), cvt_pk_bf16(a1.z, a1.w) };
                const int slot = ssl0 + 8 * i;
                *(uint4*)(&As[buf ^ 1][srow * P + ((slot ^ (srow & 7)) << 3)]) = pk;
            }
            // issue granule ks loads for next tile
            if (more && ks < IST) {
                const float* gp = x + (size_t)(nrow0 + srow) * P + (ssl0 + 8 * ks) * 8;
                ga[ks % WIN] = *(const float4*)(gp);
                gb[ks % WIN] = *(const float4*)(gp + 4);
            }
            // fragments + MFMA
            short8 af[4];
#pragma unroll
            for (int rf = 0; rf < 4; rf++) {
                const int row = 16 * rf + l15;
                const int slotIdx = (ppoff >> 3) + ks * 4 + l4;
                af[rf] = *(const short8*)(&As[buf][row * P + ((slotIdx ^ (row & 7)) << 3)]);
            }
#pragma unroll
            for (int rf = 0; rf < 4; rf++) {
                acc[0][rf] = __builtin_amdgcn_mfma_f32_16x16x32_bf16(Bf[0][ks], af[rf], acc[0][rf], 0, 0, 0);
                acc[1][rf] = __builtin_amdgcn_mfma_f32_16x16x32_bf16(Bf[1][ks], af[rf], acc[1][rf], 0, 0, 0);
            }
        }

        // tail: consume remaining granules (s0 only: granules KSW-WIN..IST-1)
        if (more) {
#pragma unroll
            for (int i = (KSW - WIN < 0 ? 0 : KSW - WIN); i < IST; i++) {
                float4 a0 = ga[i % WIN], a1 = gb[i % WIN];
                ssn += a0.x*a0.x + a0.y*a0.y + a0.z*a0.z + a0.w*a0.w
                     + a1.x*a1.x + a1.y*a1.y + a1.z*a1.z + a1.w*a1.w;
                uint4 pk = { cvt_pk_bf16(a0.x, a0.y), cvt_pk_bf16(a0.z, a0.w),
                             cvt_pk_bf16(a1.x, a1.y), cvt_pk_bf16(a1.z, a1.w) };
                const int slot = ssl0 + 8 * i;
                *(uint4*)(&As[buf ^ 1][srow * P + ((slot ^ (srow & 7)) << 3)]) = pk;
            }
            ssn += __shfl_xor(ssn, 1);
            ssn += __shfl_xor(ssn, 2);
            ssn += __shfl_xor(ssn, 4);
            if (ssl0 == 0) xn2s[buf ^ 1][srow] = ssn;
        }
        __syncthreads();   // sync1: accs final, next tile staged

        if constexpr (PPS) {
            // partner-wave partial-acc exchange through dead As[buf]
            f32x4* exch = (f32x4*)&As[buf][0];
            if (pp == 1) {
#pragma unroll
                for (int typ = 0; typ < 2; typ++)
#pragma unroll
                    for (int rf = 0; rf < 4; rf++)
                        exch[((kset * 2 + typ) * 4 + rf) * 64 + lane] = acc[typ][rf];
            }
            __syncthreads();  // sync2
            if (pp == 0) {
#pragma unroll
                for (int typ = 0; typ < 2; typ++)
#pragma unroll
                    for (int rf = 0; rf < 4; rf++) {
                        f32x4 o = exch[((kset * 2 + typ) * 4 + rf) * 64 + lane];
                        acc[typ][rf] += o;
                    }
            }
        }

        // epilogue (s0: pp==0 waves only; s1/s2: all waves)
        if (!PPS || pp == 0) {
#pragma unroll
            for (int rf = 0; rf < 4; rf++) {
                const int row = 16 * rf + l15;
                const float xv = xn2s[buf][row];
                float hs = 0.f, ms = 0.f, gs = 0.f;
#pragma unroll
                for (int j = 0; j < 4; j++) {
                    float d2 = xv - 2.f * acc[0][rf][j] + wn2[j];
                    float a  = __expf(-g2[j] * d2);
                    float ah = a * hv[j];
                    hs += ah;
                    ms += (acc[1][rf][j] + alv[j]) * ah;
                    gs += s2v[j] * ah * ah;
                }
                hs += __shfl_xor(hs, 16); hs += __shfl_xor(hs, 32);
                ms += __shfl_xor(ms, 16); ms += __shfl_xor(ms, 32);
                gs += __shfl_xor(gs, 16); gs += __shfl_xor(gs, 32);
                if (l4 == 0) { part[kset][row][0] = hs; part[kset][row][1] = ms; part[kset][row][2] = gs; }
            }
        }
        __syncthreads();  // sync3

        if (tid < 192) {
            constexpr int NG = PPS ? 4 : 8;
            const int v = tid >> 6, r = tid & 63;
            float sum = 0.f;
#pragma unroll
            for (int g = 0; g < NG; g++) sum += part[g][r][v];
            pws[(size_t)(h * 3 + v) * NT + row0 + r] = sum;
        }
        // no barrier needed: next writes to part happen after next sync1/sync2
        buf ^= 1;
    }
}

// ---------------- combine: all outputs from partials ----------------
__global__ void combine_kernel(const float* __restrict__ pws,
                               const float* __restrict__ d0, const float* __restrict__ d1,
                               const float* __restrict__ d2, float* __restrict__ out) {
    const int t = blockIdx.x * 256 + threadIdx.x;
    const int ng[3]  = {4, 2, 2};
    const int off[3] = {0, 12, 18};
    float mux[3], s2x[3], hx[3];
#pragma unroll
    for (int s = 0; s < 3; s++) {
        const float* b = pws + (size_t)off[s] * NT;
        float hh = 0.f, mm = 0.f, gg = 0.f;
        for (int g = 0; g < ng[s]; g++) {
            hh += b[(size_t)(g * 3 + 0) * NT + t];
            mm += b[(size_t)(g * 3 + 1) * NT + t];
            gg += b[(size_t)(g * 3 + 2) * NT + t];
        }
        mux[s] = mm / hh; s2x[s] = gg / (hh * hh); hx[s] = hh;
        out[(size_t)s * NT + t]       = mux[s];
        out[(size_t)(4 + s) * NT + t] = s2x[s];
        out[(size_t)(8 + s) * NT + t] = hh;
    }
    const float sd0 = 1.f / (1.f + __expf(-d0[0]));
    const float sd1 = 1.f / (1.f + __expf(-d1[0]));
    const float sd2 = 1.f / (1.f + __expf(-d2[0]));
    const float c0 = hx[0] * sd0, c1 = hx[1] * sd1, c2 = hx[2] * sd2;
    const float den = c0 + c1 + c2;
    const float muc = mux[0] * c0 + mux[1] * c1 + mux[2] * c2;
    const float sgc = s2x[0] * c0 * c0 + s2x[1] * c1 * c1 + s2x[2] * c2 * c2;
    out[(size_t)3 * NT + t]  = muc / den;
    out[(size_t)7 * NT + t]  = sgc / (den * den);
    out[(size_t)11 * NT + t] = den;
}

extern "C" void kernel_launch(void* const* d_in, const int* in_sizes, int n_in,
                              void* d_out, int out_size, void* d_ws, size_t ws_size,
                              hipStream_t stream) {
    // input order per source i: x=8i, alpha=8i+1, beta=8i+2, sig=8i+3, eta=8i+4, gam=8i+5, w=8i+6, disc=8i+7
    const float* x0 = (const float*)d_in[0];
    const float* x1 = (const float*)d_in[8];
    const float* x2 = (const float*)d_in[16];

    unsigned short* bc = (unsigned short*)d_ws;                  // 512*(512+256+128) ushorts = 917504 B
    float* prmAll = (float*)((char*)d_ws + 917504);              // 3*1280 floats = 15360 B
    float* pws    = (float*)((char*)d_ws + 917504 + 15360);      // 24*NT floats = 6.29 MB
    float* out = (float*)d_out;

    const int Ps[3] = {512, 256, 128};
    const size_t bcoff[3] = {0, 512 * 512, 512 * 512 + 512 * 256};
    for (int s = 0; s < 3; s++) {
        prep_kernel<<<512, 128, 0, stream>>>((const float*)d_in[8 * s + 6], (const float*)d_in[8 * s + 2],
                                             (const float*)d_in[8 * s + 1], (const float*)d_in[8 * s + 3],
                                             (const float*)d_in[8 * s + 4], (const float*)d_in[8 * s + 5],
                                             bc + bcoff[s], prmAll + s * 1280, Ps[s]);
    }
    fused_src<512><<<256, 512, 0, stream>>>(x0, bc + bcoff[0], prmAll,        pws);
    fused_src<256><<<256, 512, 0, stream>>>(x1, bc + bcoff[1], prmAll + 1280, pws + (size_t)12 * NT);
    fused_src<128><<<256, 512, 0, stream>>>(x2, bc + bcoff[2], prmAll + 2560, pws + (size_t)18 * NT);
    combine_kernel<<<256, 256, 0, stream>>>(pws, (const float*)d_in[7], (const float*)d_in[15],
                                            (const float*)d_in[23], out);
}